// Round 9
// baseline (817.538 us; speedup 1.0000x reference)
//
#include <hip/hip_runtime.h>

// ---------------------------------------------------------------------------
// JointlyTrainModel round 9:
//  - cheb: seg2 W-frags in per-wave registers (loaded from L2-resident WTf at
//    chunk start, used in ph4 -> latency hidden). Bs 24->16 KB, LDS ~52.5 KB
//    -> 3 blocks/CU (was 2).  [R8: 66% combined busy, barrier-latency bound]
//  - head1: bf16 feats shadow F16 written in cheb epilogue (RTNE, identical
//    numerics to staging-time conversion); head1 A-stage = 1 b128 load.
//  - ws 211.7 MB (< 256 MiB cap; R3 crash at 276.7 MB, R2 pass at 197 MB).
// ---------------------------------------------------------------------------

#define NODES   62
#define BATCH   2048
#define NTOT    (NODES * BATCH)     // 126976
#define IN_DIM  128
#define OUT_DIM 62
#define ACOLS   248                 // 4*62 activation cols
#define FEAT    15376               // 62*248
#define LIN1    512
#define LIN2    256
#define NCLS    3
#define BN_EPS  1e-5f
#define FSTR    36                  // fp32 LDS row stride (floats): 144B rows
#define BSTR    40                  // bf16 LDS row stride in head1 (ushorts)

typedef __attribute__((ext_vector_type(8)))  short  short8;
typedef __attribute__((ext_vector_type(4)))  float  f32x4;
typedef __attribute__((ext_vector_type(16))) float  f32x16;

__device__ inline unsigned short f2bf(float x) {   // RTNE (head1 path)
    unsigned u = __builtin_bit_cast(unsigned, x);
    return (unsigned short)((u + 0x7fffu + ((u >> 16) & 1u)) >> 16);
}
__device__ inline float bf2f(unsigned short h) {
    return __builtin_bit_cast(float, (unsigned)h << 16);
}
// truncation hi/lo split: x ~= hi + lo, |err| ~ 2^-16 |x|
__device__ inline void tsplit(float x, unsigned short& hi, unsigned short& lo) {
    unsigned u = __builtin_bit_cast(unsigned, x);
    hi = (unsigned short)(u >> 16);
    float r = x - __builtin_bit_cast(float, u & 0xffff0000u);
    lo = (unsigned short)(__builtin_bit_cast(unsigned, r) >> 16);
}

// ---------------------------------------------------------------------------
// Build dense T1 = L~ and T2 = 2 L~^2 - I (64x64 fp32, zero-padded).
// ---------------------------------------------------------------------------
__global__ __launch_bounds__(64) void build_LT(
    const int* __restrict__ ei, int E, int epg,
    float* __restrict__ T1g, float* __restrict__ T2g)
{
    __shared__ float Ls[NODES * NODES];
    __shared__ int   deg[NODES];
    __shared__ float dinv[NODES];
    const int t = threadIdx.x;
    for (int i = t; i < NODES * NODES; i += 64) Ls[i] = 0.f;
    if (t < NODES) deg[t] = 0;
    __syncthreads();
    const int* row = ei;
    const int* col = ei + E;
    for (int j = t; j < epg; j += 64) atomicAdd(&deg[row[j]], 1);
    __syncthreads();
    if (t < NODES) dinv[t] = (deg[t] > 0) ? rsqrtf((float)deg[t]) : 0.f;
    __syncthreads();
    for (int j = t; j < epg; j += 64) {
        int r = row[j], c = col[j];
        atomicAdd(&Ls[r * NODES + c], -dinv[r] * dinv[c]);
    }
    __syncthreads();
    const int r = t;
    for (int c = 0; c < 64; ++c) {
        float t1 = 0.f, t2 = 0.f;
        if (r < NODES && c < NODES) {
            t1 = Ls[r * NODES + c];
            float s = 0.f;
            for (int j = 0; j < NODES; ++j) s += Ls[r * NODES + j] * Ls[j * NODES + c];
            t2 = 2.f * s - (r == c ? 1.f : 0.f);
        }
        T1g[r * 64 + c] = t1;
        T2g[r * 64 + c] = t2;
    }
}

// ---------------------------------------------------------------------------
// T1/T2 -> A-fragment order hi/lo for mfma 32x32x16.
// ---------------------------------------------------------------------------
__global__ __launch_bounds__(256) void conv_T(
    const float* __restrict__ T1g, const float* __restrict__ T2g,
    unsigned short* __restrict__ Tf)
{
    int idx = blockIdx.x * 256 + threadIdx.x;
    if (idx >= 16384) return;
    int j    = idx & 7;
    int lane = (idx >> 3) & 63;
    int pl   = (idx >> 9) & 1;
    int ks   = (idx >> 10) & 3;
    int w    = (idx >> 12) & 3;
    int m = (w & 1) * 32 + (lane & 31);
    int k = ks * 16 + (lane >> 5) * 8 + j;
    float v = (w >> 1) ? T2g[m * 64 + k] : T1g[m * 64 + k];
    unsigned short hi, lo;
    tsplit(v, hi, lo);
    Tf[idx] = pl ? lo : hi;
}

// H[b, 0:C] = bias broadcast.
__global__ __launch_bounds__(256) void init_bias(
    float* __restrict__ H, const float* __restrict__ bias, int c4mask, int total4)
{
    int i = blockIdx.x * 256 + threadIdx.x;
    if (i < total4)
        ((float4*)H)[i] = ((const float4*)bias)[i & c4mask];
}

// ---------------------------------------------------------------------------
// Cheb weights -> 32x32x16 B-fragment order, hi/lo. 24 KB/chunk contiguous;
// segs 0,1 are frags 0..15 (16 KB, staged to LDS), seg2 frags 16..23 (regs).
// ---------------------------------------------------------------------------
__global__ __launch_bounds__(256) void conv_wcheb(
    const float* __restrict__ W, unsigned short* __restrict__ WTf, int d, int dpad)
{
    const int total = (dpad >> 5) * 12288;
    int idx = blockIdx.x * 256 + threadIdx.x;
    if (idx >= total) return;
    int j    = idx & 7;
    int lane = (idx >> 3) & 63;
    int f    = idx >> 9;
    int nt   = f & 1;
    int pl   = (f >> 1) & 1;
    int ks   = (f >> 2) & 1;
    int seg  = (f >> 3) % 3;
    int ch   = (f >> 3) / 3;
    int n  = nt * 32 + (lane & 31);
    int kk = ch * 32 + ks * 16 + (lane >> 5) * 8 + j;
    float v = (n < NODES && kk < d) ? W[((size_t)seg * d + kk) * OUT_DIM + n] : 0.f;
    unsigned short hi, lo;
    tsplit(v, hi, lo);
    WTf[idx] = pl ? lo : hi;
}

// ---------------------------------------------------------------------------
// Wh1 [15376][512] fp32 -> Wh1T [512][15376] bf16 via LDS 32x32 transpose.
// ---------------------------------------------------------------------------
__global__ __launch_bounds__(256) void transpose_wh1(
    const float* __restrict__ W, unsigned short* __restrict__ WT)
{
    __shared__ float T[32][33];
    const int k0 = blockIdx.x * 32, n0 = blockIdx.y * 32;
    {
        int kl = threadIdx.x >> 3, n4 = (threadIdx.x & 7) * 4;
        if (k0 + kl < FEAT) {
            float4 v = *(const float4*)&W[(size_t)(k0 + kl) * LIN1 + n0 + n4];
            T[kl][n4] = v.x; T[kl][n4 + 1] = v.y; T[kl][n4 + 2] = v.z; T[kl][n4 + 3] = v.w;
        }
    }
    __syncthreads();
    {
        int nl = threadIdx.x >> 3, k4 = (threadIdx.x & 7) * 4;
        if (k0 + k4 + 3 < FEAT) {
            ushort4 o;
            o.x = f2bf(T[k4 + 0][nl]);
            o.y = f2bf(T[k4 + 1][nl]);
            o.z = f2bf(T[k4 + 2][nl]);
            o.w = f2bf(T[k4 + 3][nl]);
            *(ushort4*)&WT[(size_t)(n0 + nl) * FEAT + k0 + k4] = o;
        }
    }
}

// ---------------------------------------------------------------------------
// Fused Cheb layer, 3 barriers/chunk, register-pipelined loads, seg2 W in
// registers. Epilogue writes fp32 (next layer) + bf16 RTNE (head GEMM).
// ---------------------------------------------------------------------------
__global__ __launch_bounds__(256, 2) void cheb_mfma(
    const float* __restrict__ x, float* __restrict__ X248,
    unsigned short* __restrict__ F16,
    const unsigned short* __restrict__ WTf, const unsigned short* __restrict__ Tf,
    const float* __restrict__ bias, int d, int dpad)
{
    __shared__ __align__(16) float hr [64 * FSTR];
    __shared__ __align__(16) float t1r[64 * FSTR];
    __shared__ __align__(16) float t2r[64 * FSTR];
    __shared__ __align__(16) unsigned short hBf[8 * 512];    //  8 KB
    __shared__ __align__(16) unsigned short Bs[16 * 512];    // 16 KB (segs 0,1)
    __shared__ float bias_s[64];

    const int tid  = threadIdx.x;
    const int g    = blockIdx.x;
    const int lane = tid & 63;
    const int wv   = tid >> 6;

    // permanent T-fragments for this wave: [kstep][plane]
    short8 Tfr[4][2];
    #pragma unroll
    for (int ks = 0; ks < 4; ++ks)
        #pragma unroll
        for (int pl = 0; pl < 2; ++pl)
            Tfr[ks][pl] = *(const short8*)(Tf + (((size_t)(wv * 4 + ks) * 2 + pl) << 9) + lane * 8);

    if (tid < 64) bias_s[tid] = (tid < OUT_DIM) ? bias[tid] : 0.f;

    f32x16 acc;
    #pragma unroll
    for (int i = 0; i < 16; ++i) acc[i] = 0.f;

    const int fcol = tid & 31, rblk = tid >> 5;   // staging map
    const int kst = rblk >> 1, lh = rblk & 1;     // hBf target
    const int nchunk = dpad >> 5;
    const int mtw = wv >> 1, ntw = wv & 1;        // ph4/epilogue tile

#define LOADCH(cn)                                                             \
    do {                                                                       \
        const int gf_ = (cn) * 32 + fcol;                                      \
        const bool fromx_ = ((cn) * 32 < IN_DIM);                              \
        _Pragma("unroll")                                                      \
        for (int p = 0; p < 8; ++p) {                                          \
            int r_ = rblk * 8 + p;                                             \
            float v_ = 0.f;                                                    \
            if (r_ < NODES && gf_ < d)                                         \
                v_ = fromx_ ? x[(size_t)(g * NODES + r_) * IN_DIM + gf_]       \
                            : X248[(size_t)(g * NODES + r_) * ACOLS + (gf_ - IN_DIM)]; \
            vh[p] = v_;                                                        \
        }                                                                      \
        const short8* wsrc_ = (const short8*)(WTf + (size_t)(cn) * 12288);     \
        _Pragma("unroll")                                                      \
        for (int i = 0; i < 4; ++i) breg[i] = wsrc_[i * 256 + tid];            \
        _Pragma("unroll")                                                      \
        for (int ks_ = 0; ks_ < 2; ++ks_)                                      \
            _Pragma("unroll")                                                  \
            for (int pl_ = 0; pl_ < 2; ++pl_)                                  \
                wreg2[ks_ * 2 + pl_] = *(const short8*)(WTf + (size_t)(cn) * 12288 \
                    + ((16 + 4 * ks_ + 2 * pl_ + ntw) << 9) + lane * 8);       \
    } while (0)

    float  vh[8];
    short8 breg[4];
    short8 wreg2[4];   // seg2 W-frags for this wave's ntw: [ks][pl]
    LOADCH(0);   // prologue

    for (int ch = 0; ch < nchunk; ++ch) {
        // ---- ph1: write staged data from registers
        {
            short8 hi8, lo8;
            #pragma unroll
            for (int p = 0; p < 8; ++p) {
                unsigned short h_, l_;
                tsplit(vh[p], h_, l_);
                hi8[p] = (short)h_; lo8[p] = (short)l_;
                hr[(rblk * 8 + p) * FSTR + fcol] = vh[p];
            }
            const int dlane = lh * 32 + fcol;
            *(short8*)&hBf[((kst * 2 + 0) << 9) + dlane * 8] = hi8;
            *(short8*)&hBf[((kst * 2 + 1) << 9) + dlane * 8] = lo8;
            #pragma unroll
            for (int i = 0; i < 4; ++i) ((short8*)Bs)[i * 256 + tid] = breg[i];
        }
        __syncthreads();   // A
        // ---- ph3: P = T@h (waves 0,1 -> T1 tiles; 2,3 -> T2 tiles)
        {
            f32x16 pacc;
            #pragma unroll
            for (int i = 0; i < 16; ++i) pacc[i] = 0.f;
            #pragma unroll
            for (int ks = 0; ks < 4; ++ks) {
                short8 bhi = *(const short8*)&hBf[((ks * 2 + 0) << 9) + lane * 8];
                short8 blo = *(const short8*)&hBf[((ks * 2 + 1) << 9) + lane * 8];
                pacc = __builtin_amdgcn_mfma_f32_32x32x16_bf16(Tfr[ks][0], bhi, pacc, 0, 0, 0);
                pacc = __builtin_amdgcn_mfma_f32_32x32x16_bf16(Tfr[ks][0], blo, pacc, 0, 0, 0);
                pacc = __builtin_amdgcn_mfma_f32_32x32x16_bf16(Tfr[ks][1], bhi, pacc, 0, 0, 0);
            }
            float* dst = (wv < 2) ? t1r : t2r;
            const int mbase = (wv & 1) * 32 + 4 * (lane >> 5);
            const int ccol  = lane & 31;
            #pragma unroll
            for (int reg = 0; reg < 16; ++reg) {
                int rr = mbase + (reg & 3) + 8 * (reg >> 2);
                dst[rr * FSTR + ccol] = pacc[reg];
            }
        }
        __syncthreads();   // B
        // ---- ph4: issue next-chunk loads (drain at barrier C), then MFMA
        {
            short8 wr2s[4];
            #pragma unroll
            for (int i = 0; i < 4; ++i) wr2s[i] = wreg2[i];
            if (ch + 1 < nchunk) LOADCH(ch + 1);
            #pragma unroll
            for (int seg = 0; seg < 3; ++seg) {
                const float* src = (seg == 0) ? hr : (seg == 1) ? t1r : t2r;
                #pragma unroll
                for (int ks = 0; ks < 2; ++ks) {
                    const int kf = ks * 16 + (lane >> 5) * 8;
                    const float* ap = &src[(mtw * 32 + (lane & 31)) * FSTR + kf];
                    f32x4 u0 = *(const f32x4*)ap;
                    f32x4 u1 = *(const f32x4*)(ap + 4);
                    short8 ahi, alo;
                    #pragma unroll
                    for (int j = 0; j < 4; ++j) {
                        unsigned short h_, l_;
                        tsplit(u0[j], h_, l_); ahi[j] = (short)h_; alo[j] = (short)l_;
                        tsplit(u1[j], h_, l_); ahi[4 + j] = (short)h_; alo[4 + j] = (short)l_;
                    }
                    short8 bhi, blo;
                    if (seg < 2) {
                        const unsigned short* bp =
                            Bs + ((((seg * 2 + ks) * 2 + 0) * 2 + ntw) << 9) + lane * 8;
                        bhi = *(const short8*)bp;
                        blo = *(const short8*)(bp + 1024);   // +1 plane = +2 frags
                    } else {
                        bhi = wr2s[ks * 2 + 0];
                        blo = wr2s[ks * 2 + 1];
                    }
                    acc = __builtin_amdgcn_mfma_f32_32x32x16_bf16(ahi, bhi, acc, 0, 0, 0);
                    acc = __builtin_amdgcn_mfma_f32_32x32x16_bf16(ahi, blo, acc, 0, 0, 0);
                    acc = __builtin_amdgcn_mfma_f32_32x32x16_bf16(alo, bhi, acc, 0, 0, 0);
                }
            }
        }
        __syncthreads();   // C (protects hr/hBf/Bs/t1r/t2r overwrite)
    }
#undef LOADCH
    // epilogue: relu(acc + bias) -> X248 fp32 + F16 bf16 (RTNE)
    {
        const int c = ntw * 32 + (lane & 31);
        if (c < OUT_DIM) {
            const int mbase = mtw * 32 + 4 * (lane >> 5);
            #pragma unroll
            for (int reg = 0; reg < 16; ++reg) {
                int m = mbase + (reg & 3) + 8 * (reg >> 2);
                if (m < NODES) {
                    float v = fmaxf(acc[reg] + bias_s[c], 0.f);
                    X248[(size_t)(g * NODES + m) * ACOLS + (d - IN_DIM) + c] = v;
                    F16[(size_t)g * FEAT + m * ACOLS + (d - IN_DIM) + c] = f2bf(v);
                }
            }
        }
    }
}

// ---------------------------------------------------------------------------
// Head GEMM1, bf16 MFMA, 64x128 tile, split-K=8: H1 += feats @ Wh1.
// feats now pre-converted bf16 (F16): A-stage = 1 b128 load, no VALU.
// Grid (32, 4, 8) = 1024 blocks (all resident).
// ---------------------------------------------------------------------------
#define SPLIT1 8
__global__ __launch_bounds__(256) void gemm_head1_mfma(
    const unsigned short* __restrict__ F16, const unsigned short* __restrict__ WT1,
    float* __restrict__ H1)
{
    __shared__ __align__(16) unsigned short A16[64 * BSTR];
    __shared__ __align__(16) unsigned short B16[128 * BSTR];
    const int tid  = threadIdx.x;
    const int lane = tid & 63;
    const int wv   = tid >> 6;
    const int bm = blockIdx.x, bnb = blockIdx.y, s = blockIdx.z;
    const int c0 = (481 * s) / SPLIT1, c1 = (481 * (s + 1)) / SPLIT1;
    const int mr = tid >> 2, kg = (tid & 3) * 8;      // A stage map
    const int mrB = tid >> 1, kgB = (tid & 1) * 16;   // B stage map

    f32x4 acc[8];
    #pragma unroll
    for (int i = 0; i < 8; ++i) acc[i] = (f32x4){0.f, 0.f, 0.f, 0.f};

    for (int ch = c0; ch < c1; ++ch) {
        const int k = ch * 32 + kg;
        short8 av = {0, 0, 0, 0, 0, 0, 0, 0};
        if (k + 8 <= FEAT)   // FEAT % 8 == 0 -> all-or-nothing groups
            av = *(const short8*)&F16[(size_t)(bm * 64 + mr) * FEAT + k];
        short8 bv0 = {0, 0, 0, 0, 0, 0, 0, 0};
        short8 bv1 = {0, 0, 0, 0, 0, 0, 0, 0};
        const int kB = ch * 32 + kgB;
        if (kB + 8 <= FEAT)
            bv0 = *(const short8*)&WT1[(size_t)(bnb * 128 + mrB) * FEAT + kB];
        if (kB + 16 <= FEAT)
            bv1 = *(const short8*)&WT1[(size_t)(bnb * 128 + mrB) * FEAT + kB + 8];
        *(short8*)&A16[mr * BSTR + kg] = av;
        *(short8*)&B16[mrB * BSTR + kgB] = bv0;
        *(short8*)&B16[mrB * BSTR + kgB + 8] = bv1;
        __syncthreads();
        short8 af = *(short8*)&A16[(wv * 16 + (lane & 15)) * BSTR + (lane >> 4) * 8];
        #pragma unroll
        for (int nt = 0; nt < 8; ++nt) {
            short8 bf = *(short8*)&B16[(nt * 16 + (lane & 15)) * BSTR + (lane >> 4) * 8];
            acc[nt] = __builtin_amdgcn_mfma_f32_16x16x32_bf16(af, bf, acc[nt], 0, 0, 0);
        }
        __syncthreads();
    }
    const int m0 = bm * 64 + wv * 16 + (lane >> 4) * 4;
    #pragma unroll
    for (int nt = 0; nt < 8; ++nt) {
        int c = bnb * 128 + nt * 16 + (lane & 15);
        #pragma unroll
        for (int rg = 0; rg < 4; ++rg)
            atomicAdd(&H1[(size_t)(m0 + rg) * LIN1 + c], acc[nt][rg]);
    }
}

// ---------------------------------------------------------------------------
// GEMM2 fp32 (split-K=4): H2 += H1[2048,512] @ Wh2.
// ---------------------------------------------------------------------------
#define ACC16(av, bv) do {                              \
    acc[0][0] = fmaf((av).x, (bv).x, acc[0][0]);        \
    acc[0][1] = fmaf((av).x, (bv).y, acc[0][1]);        \
    acc[0][2] = fmaf((av).x, (bv).z, acc[0][2]);        \
    acc[0][3] = fmaf((av).x, (bv).w, acc[0][3]);        \
    acc[1][0] = fmaf((av).y, (bv).x, acc[1][0]);        \
    acc[1][1] = fmaf((av).y, (bv).y, acc[1][1]);        \
    acc[1][2] = fmaf((av).y, (bv).z, acc[1][2]);        \
    acc[1][3] = fmaf((av).y, (bv).w, acc[1][3]);        \
    acc[2][0] = fmaf((av).z, (bv).x, acc[2][0]);        \
    acc[2][1] = fmaf((av).z, (bv).y, acc[2][1]);        \
    acc[2][2] = fmaf((av).z, (bv).z, acc[2][2]);        \
    acc[2][3] = fmaf((av).z, (bv).w, acc[2][3]);        \
    acc[3][0] = fmaf((av).w, (bv).x, acc[3][0]);        \
    acc[3][1] = fmaf((av).w, (bv).y, acc[3][1]);        \
    acc[3][2] = fmaf((av).w, (bv).z, acc[3][2]);        \
    acc[3][3] = fmaf((av).w, (bv).w, acc[3][3]);        \
} while (0)

#define SPLIT2 4
__global__ __launch_bounds__(256) void gemm2_kernel(
    const float* __restrict__ A, const float* __restrict__ B,
    float* __restrict__ C)
{
    __shared__ __align__(16) float As[16 * 72];
    __shared__ __align__(16) float Bs[16 * 64];
    const int bm = blockIdx.x, bnb = blockIdx.y, s = blockIdx.z;
    const int tid = threadIdx.x;
    const int ty4 = (tid >> 4) * 4;
    const int tx4 = (tid & 15) * 4;
    const int kbeg = s * (LIN1 / SPLIT2);
    const int kend = kbeg + LIN1 / SPLIT2;
    float acc[4][4] = {};
    for (int k0 = kbeg; k0 < kend; k0 += 16) {
        for (int i = tid; i < 1024; i += 256) {
            int m = i >> 4, kt = i & 15;
            As[kt * 72 + m] = A[(size_t)(bm * 64 + m) * LIN1 + k0 + kt];
        }
        for (int i = tid; i < 1024; i += 256) {
            int kt = i >> 6, c = i & 63;
            Bs[kt * 64 + c] = B[(size_t)(k0 + kt) * LIN2 + bnb * 64 + c];
        }
        __syncthreads();
        #pragma unroll
        for (int kt = 0; kt < 16; ++kt) {
            const float4 av = *(const float4*)&As[kt * 72 + ty4];
            const float4 bv = *(const float4*)&Bs[kt * 64 + tx4];
            ACC16(av, bv);
        }
        __syncthreads();
    }
    const int b = bm * 64 + ty4, c = bnb * 64 + tx4;
    #pragma unroll
    for (int i = 0; i < 4; ++i)
        #pragma unroll
        for (int j = 0; j < 4; ++j)
            atomicAdd(&C[(size_t)(b + i) * LIN2 + c + j], acc[i][j]);
}

// ---------------------------------------------------------------------------
// BatchNorm (training stats, biased var) + ReLU, in place.
// ---------------------------------------------------------------------------
__global__ __launch_bounds__(256) void bn_relu_kernel(
    float* __restrict__ H, int C,
    const float* __restrict__ gamma, const float* __restrict__ beta)
{
    const int c  = blockIdx.x * 16 + (threadIdx.x & 15);
    const int rt = threadIdx.x >> 4;
    const int ct = threadIdx.x & 15;
    float s = 0.f, s2 = 0.f;
    for (int r = rt; r < BATCH; r += 16) {
        float v = H[(size_t)r * C + c];
        s += v; s2 += v * v;
    }
    __shared__ float Ss[16][16], S2s[16][16], sc_s[16], sh_s[16];
    Ss[rt][ct] = s; S2s[rt][ct] = s2;
    __syncthreads();
    if (rt == 0) {
        float ts = 0.f, ts2 = 0.f;
        #pragma unroll
        for (int i = 0; i < 16; ++i) { ts += Ss[i][ct]; ts2 += S2s[i][ct]; }
        float m   = ts * (1.f / BATCH);
        float var = ts2 * (1.f / BATCH) - m * m;
        float sc  = gamma[c] * rsqrtf(var + BN_EPS);
        sc_s[ct] = sc;
        sh_s[ct] = beta[c] - m * sc;
    }
    __syncthreads();
    const float sc = sc_s[ct], sh = sh_s[ct];
    for (int r = rt; r < BATCH; r += 16) {
        float v = H[(size_t)r * C + c];
        H[(size_t)r * C + c] = fmaxf(fmaf(v, sc, sh), 0.f);
    }
}

// ---------------------------------------------------------------------------
// Final: logits = H2 @ Wh3 + bh3, softmax over 3 classes.
// ---------------------------------------------------------------------------
__global__ __launch_bounds__(256) void final_kernel(
    const float* __restrict__ H2, const float* __restrict__ Wh3,
    const float* __restrict__ bh3, float* __restrict__ out)
{
    __shared__ float Ws[LIN2 * NCLS];
    __shared__ float bs[NCLS];
    const int tid = threadIdx.x;
    for (int i = tid; i < LIN2 * NCLS; i += 256) Ws[i] = Wh3[i];
    if (tid < NCLS) bs[tid] = bh3[tid];
    __syncthreads();
    const int r = blockIdx.x * 256 + tid;
    float a0 = bs[0], a1 = bs[1], a2 = bs[2];
    const float4* row = (const float4*)&H2[(size_t)r * LIN2];
    for (int k4 = 0; k4 < LIN2 / 4; ++k4) {
        float4 h = row[k4];
        int k = k4 * 4;
        a0 = fmaf(h.x, Ws[(k + 0) * 3 + 0], a0);
        a1 = fmaf(h.x, Ws[(k + 0) * 3 + 1], a1);
        a2 = fmaf(h.x, Ws[(k + 0) * 3 + 2], a2);
        a0 = fmaf(h.y, Ws[(k + 1) * 3 + 0], a0);
        a1 = fmaf(h.y, Ws[(k + 1) * 3 + 1], a1);
        a2 = fmaf(h.y, Ws[(k + 1) * 3 + 2], a2);
        a0 = fmaf(h.z, Ws[(k + 2) * 3 + 0], a0);
        a1 = fmaf(h.z, Ws[(k + 2) * 3 + 1], a1);
        a2 = fmaf(h.z, Ws[(k + 2) * 3 + 2], a2);
        a0 = fmaf(h.w, Ws[(k + 3) * 3 + 0], a0);
        a1 = fmaf(h.w, Ws[(k + 3) * 3 + 1], a1);
        a2 = fmaf(h.w, Ws[(k + 3) * 3 + 2], a2);
    }
    float mx = fmaxf(a0, fmaxf(a1, a2));
    float e0 = expf(a0 - mx), e1 = expf(a1 - mx), e2 = expf(a2 - mx);
    float inv = 1.f / (e0 + e1 + e2);
    out[r * 3 + 0] = e0 * inv;
    out[r * 3 + 1] = e1 * inv;
    out[r * 3 + 2] = e2 * inv;
}

// ---------------------------------------------------------------------------
extern "C" void kernel_launch(void* const* d_in, const int* in_sizes, int n_in,
                              void* d_out, int out_size, void* d_ws, size_t ws_size,
                              hipStream_t stream)
{
    const float* x   = (const float*)d_in[0];
    const int*   ei  = (const int*)  d_in[1];
    const float* W1  = (const float*)d_in[2];
    const float* b1  = (const float*)d_in[3];
    const float* W2  = (const float*)d_in[4];
    const float* b2  = (const float*)d_in[5];
    const float* W3  = (const float*)d_in[6];
    const float* b3  = (const float*)d_in[7];
    const float* W4  = (const float*)d_in[8];
    const float* b4  = (const float*)d_in[9];
    const float* Wh1 = (const float*)d_in[10];
    const float* bh1 = (const float*)d_in[11];
    const float* g1  = (const float*)d_in[12];
    const float* be1 = (const float*)d_in[13];
    const float* Wh2 = (const float*)d_in[14];
    const float* bh2 = (const float*)d_in[15];
    const float* g2  = (const float*)d_in[16];
    const float* be2 = (const float*)d_in[17];
    const float* Wh3 = (const float*)d_in[18];
    const float* bh3 = (const float*)d_in[19];
    float* out = (float*)d_out;

    // workspace layout -- TOTAL 211,730,432 B (< 256 MiB cap)
    char* ws = (char*)d_ws;
    float* T1g = (float*)(ws + 0);                                   // 16384
    float* T2g = (float*)(ws + 16384);                               // 16384
    unsigned short* Tf   = (unsigned short*)(ws + 32768);            // 32768
    unsigned short* WT1c = (unsigned short*)(ws + 65536);            // 98304   (4 ch)
    unsigned short* WT2c = (unsigned short*)(ws + 163840);           // 147456  (6 ch)
    unsigned short* WT3c = (unsigned short*)(ws + 311296);           // 196608  (8 ch)
    unsigned short* WT4c = (unsigned short*)(ws + 507904);           // 245760  (10 ch)
    unsigned short* Wh1T = (unsigned short*)(ws + 753664);           // 15,745,024
    unsigned short* F16  = (unsigned short*)(ws + 16498688);         // 62,980,096
    float* X248 = (float*)(ws + 79478784);                           // 125,960,192
    float* H1   = (float*)(ws + 205438976);                          // 4,194,304
    float* H2   = (float*)(ws + 209633280);                          // 2,097,152

    const int E   = in_sizes[1] / 2;   // 1,015,808
    const int epg = E / BATCH;         // 496 edges of graph 0

    build_LT<<<1, 64, 0, stream>>>(ei, E, epg, T1g, T2g);
    conv_T<<<64, 256, 0, stream>>>(T1g, T2g, Tf);

    conv_wcheb<<<( 4 * 12288 + 255) / 256, 256, 0, stream>>>(W1, WT1c, 128, 128);
    conv_wcheb<<<( 6 * 12288 + 255) / 256, 256, 0, stream>>>(W2, WT2c, 190, 192);
    conv_wcheb<<<( 8 * 12288 + 255) / 256, 256, 0, stream>>>(W3, WT3c, 252, 256);
    conv_wcheb<<<(10 * 12288 + 255) / 256, 256, 0, stream>>>(W4, WT4c, 314, 320);
    transpose_wh1<<<dim3(481, 16), 256, 0, stream>>>(Wh1, Wh1T);

    cheb_mfma<<<BATCH, 256, 0, stream>>>(x, X248, F16, WT1c, Tf, b1, 128, 128);
    cheb_mfma<<<BATCH, 256, 0, stream>>>(x, X248, F16, WT2c, Tf, b2, 190, 192);
    cheb_mfma<<<BATCH, 256, 0, stream>>>(x, X248, F16, WT3c, Tf, b3, 252, 256);
    cheb_mfma<<<BATCH, 256, 0, stream>>>(x, X248, F16, WT4c, Tf, b4, 314, 320);

    init_bias<<<(BATCH * LIN1 / 4 + 255) / 256, 256, 0, stream>>>(H1, bh1, LIN1 / 4 - 1, BATCH * LIN1 / 4);
    gemm_head1_mfma<<<dim3(32, 4, SPLIT1), 256, 0, stream>>>(F16, Wh1T, H1);
    bn_relu_kernel<<<LIN1 / 16, 256, 0, stream>>>(H1, LIN1, g1, be1);

    init_bias<<<(BATCH * LIN2 / 4 + 255) / 256, 256, 0, stream>>>(H2, bh2, LIN2 / 4 - 1, BATCH * LIN2 / 4);
    gemm2_kernel<<<dim3(32, 4, SPLIT2), 256, 0, stream>>>(H1, Wh2, H2);
    bn_relu_kernel<<<LIN2 / 16, 256, 0, stream>>>(H2, LIN2, g2, be2);

    final_kernel<<<BATCH / 256, 256, 0, stream>>>(H2, Wh3, bh3, out);
}

// Round 10
// 751.377 us; speedup vs baseline: 1.0881x; 1.0881x over previous
//
#include <hip/hip_runtime.h>

// ---------------------------------------------------------------------------
// JointlyTrainModel round 10:
//  - cheb: revert to R8 variant (measured best: 115.6us @ d=314, conflicts 0)
//  - head1: software-pipelined (register prefetch of next chunk during MFMA;
//    R9 showed unpipelined loop at MfmaUtil 10.5%, pure latency exposure)
//  - F16 shadow dropped (ws back to 148.7 MB; R9's 211.7 MB may tax re-poison)
//  - merged pre-kernels: build_LT+conv_T -> 1 launch; 4x conv_wcheb -> 1
// ---------------------------------------------------------------------------

#define NODES   62
#define BATCH   2048
#define NTOT    (NODES * BATCH)     // 126976
#define IN_DIM  128
#define OUT_DIM 62
#define ACOLS   248                 // 4*62 activation cols
#define FEAT    15376               // 62*248
#define LIN1    512
#define LIN2    256
#define NCLS    3
#define BN_EPS  1e-5f
#define FSTR    36                  // fp32 LDS row stride (floats): 144B rows
#define BSTR    40                  // bf16 LDS row stride in head1 (ushorts)

typedef __attribute__((ext_vector_type(8)))  short  short8;
typedef __attribute__((ext_vector_type(4)))  float  f32x4;
typedef __attribute__((ext_vector_type(16))) float  f32x16;

__device__ inline unsigned short f2bf(float x) {   // RTNE (head1 path)
    unsigned u = __builtin_bit_cast(unsigned, x);
    return (unsigned short)((u + 0x7fffu + ((u >> 16) & 1u)) >> 16);
}
__device__ inline float bf2f(unsigned short h) {
    return __builtin_bit_cast(float, (unsigned)h << 16);
}
// truncation hi/lo split: x ~= hi + lo, |err| ~ 2^-16 |x|
__device__ inline void tsplit(float x, unsigned short& hi, unsigned short& lo) {
    unsigned u = __builtin_bit_cast(unsigned, x);
    hi = (unsigned short)(u >> 16);
    float r = x - __builtin_bit_cast(float, u & 0xffff0000u);
    lo = (unsigned short)(__builtin_bit_cast(unsigned, r) >> 16);
}

// ---------------------------------------------------------------------------
// Build T1 = L~, T2 = 2 L~^2 - I in LDS and emit A-frag-order hi/lo Tf.
// One block, 256 threads (merged build_LT + conv_T).
// ---------------------------------------------------------------------------
__global__ __launch_bounds__(256) void build_LT_convT(
    const int* __restrict__ ei, int E, int epg, unsigned short* __restrict__ Tf)
{
    __shared__ float Ls[NODES * NODES];
    __shared__ float Ts[2][64 * 64];
    __shared__ int   deg[NODES];
    __shared__ float dinv[NODES];
    const int t = threadIdx.x;
    for (int i = t; i < NODES * NODES; i += 256) Ls[i] = 0.f;
    if (t < NODES) deg[t] = 0;
    __syncthreads();
    const int* row = ei;
    const int* col = ei + E;
    for (int j = t; j < epg; j += 256) atomicAdd(&deg[row[j]], 1);
    __syncthreads();
    if (t < NODES) dinv[t] = (deg[t] > 0) ? rsqrtf((float)deg[t]) : 0.f;
    __syncthreads();
    for (int j = t; j < epg; j += 256) {
        int r = row[j], c = col[j];
        atomicAdd(&Ls[r * NODES + c], -dinv[r] * dinv[c]);
    }
    __syncthreads();
    for (int idx = t; idx < 4096; idx += 256) {
        int r = idx >> 6, c = idx & 63;
        float t1 = 0.f, t2 = 0.f;
        if (r < NODES && c < NODES) {
            t1 = Ls[r * NODES + c];
            float s = 0.f;
            for (int j = 0; j < NODES; ++j) s += Ls[r * NODES + j] * Ls[j * NODES + c];
            t2 = 2.f * s - (r == c ? 1.f : 0.f);
        }
        Ts[0][idx] = t1;
        Ts[1][idx] = t2;
    }
    __syncthreads();
    // frag-order emit: Tf[((w*4+ks)*2+pl)*512 + lane*8 + j]
    for (int idx = t; idx < 16384; idx += 256) {
        int j    = idx & 7;
        int lane = (idx >> 3) & 63;
        int pl   = (idx >> 9) & 1;
        int ks   = (idx >> 10) & 3;
        int w    = (idx >> 12) & 3;
        int m = (w & 1) * 32 + (lane & 31);
        int k = ks * 16 + (lane >> 5) * 8 + j;
        float v = Ts[w >> 1][m * 64 + k];
        unsigned short hi, lo;
        tsplit(v, hi, lo);
        Tf[idx] = pl ? lo : hi;
    }
}

// H[b, 0:C] = bias broadcast.
__global__ __launch_bounds__(256) void init_bias(
    float* __restrict__ H, const float* __restrict__ bias, int c4mask, int total4)
{
    int i = blockIdx.x * 256 + threadIdx.x;
    if (i < total4)
        ((float4*)H)[i] = ((const float4*)bias)[i & c4mask];
}

// ---------------------------------------------------------------------------
// All 4 cheb weight tensors -> 32x32x16 B-fragment order hi/lo, one launch.
// Layer selected by blockIdx.y. Layout identical to R7-R9 conv_wcheb.
// ---------------------------------------------------------------------------
__global__ __launch_bounds__(256) void conv_wcheb_all(
    const float* __restrict__ W1, const float* __restrict__ W2,
    const float* __restrict__ W3, const float* __restrict__ W4,
    unsigned short* __restrict__ O1, unsigned short* __restrict__ O2,
    unsigned short* __restrict__ O3, unsigned short* __restrict__ O4)
{
    const int layer = blockIdx.y;
    const float* W = (layer == 0) ? W1 : (layer == 1) ? W2 : (layer == 2) ? W3 : W4;
    unsigned short* WTf = (layer == 0) ? O1 : (layer == 1) ? O2 : (layer == 2) ? O3 : O4;
    const int d    = (layer == 0) ? 128 : (layer == 1) ? 190 : (layer == 2) ? 252 : 314;
    const int dpad = (layer == 0) ? 128 : (layer == 1) ? 192 : (layer == 2) ? 256 : 320;
    const int total = (dpad >> 5) * 12288;
    int idx = blockIdx.x * 256 + threadIdx.x;
    if (idx >= total) return;
    int j    = idx & 7;
    int lane = (idx >> 3) & 63;
    int f    = idx >> 9;
    int nt   = f & 1;
    int pl   = (f >> 1) & 1;
    int ks   = (f >> 2) & 1;
    int seg  = (f >> 3) % 3;
    int ch   = (f >> 3) / 3;
    int n  = nt * 32 + (lane & 31);
    int kk = ch * 32 + ks * 16 + (lane >> 5) * 8 + j;
    float v = (n < NODES && kk < d) ? W[((size_t)seg * d + kk) * OUT_DIM + n] : 0.f;
    unsigned short hi, lo;
    tsplit(v, hi, lo);
    WTf[idx] = pl ? lo : hi;
}

// ---------------------------------------------------------------------------
// Wh1 [15376][512] fp32 -> Wh1T [512][15376] bf16 via LDS 32x32 transpose.
// ---------------------------------------------------------------------------
__global__ __launch_bounds__(256) void transpose_wh1(
    const float* __restrict__ W, unsigned short* __restrict__ WT)
{
    __shared__ float T[32][33];
    const int k0 = blockIdx.x * 32, n0 = blockIdx.y * 32;
    {
        int kl = threadIdx.x >> 3, n4 = (threadIdx.x & 7) * 4;
        if (k0 + kl < FEAT) {
            float4 v = *(const float4*)&W[(size_t)(k0 + kl) * LIN1 + n0 + n4];
            T[kl][n4] = v.x; T[kl][n4 + 1] = v.y; T[kl][n4 + 2] = v.z; T[kl][n4 + 3] = v.w;
        }
    }
    __syncthreads();
    {
        int nl = threadIdx.x >> 3, k4 = (threadIdx.x & 7) * 4;
        if (k0 + k4 + 3 < FEAT) {
            ushort4 o;
            o.x = f2bf(T[k4 + 0][nl]);
            o.y = f2bf(T[k4 + 1][nl]);
            o.z = f2bf(T[k4 + 2][nl]);
            o.w = f2bf(T[k4 + 3][nl]);
            *(ushort4*)&WT[(size_t)(n0 + nl) * FEAT + k0 + k4] = o;
        }
    }
}

// ---------------------------------------------------------------------------
// Fused Cheb layer (R8 variant: Bs-full staging, no F16). 3 barriers/chunk,
// register-pipelined loads; dense-T prop in registers via mfma 32x32x16.
// ---------------------------------------------------------------------------
__global__ __launch_bounds__(256, 2) void cheb_mfma(
    const float* __restrict__ x, float* __restrict__ X248,
    const unsigned short* __restrict__ WTf, const unsigned short* __restrict__ Tf,
    const float* __restrict__ bias, int d, int dpad)
{
    __shared__ __align__(16) float hr [64 * FSTR];
    __shared__ __align__(16) float t1r[64 * FSTR];
    __shared__ __align__(16) float t2r[64 * FSTR];
    __shared__ __align__(16) unsigned short hBf[8 * 512];    //  8 KB
    __shared__ __align__(16) unsigned short Bs[24 * 512];    // 24 KB
    __shared__ float bias_s[64];

    const int tid  = threadIdx.x;
    const int g    = blockIdx.x;
    const int lane = tid & 63;
    const int wv   = tid >> 6;

    // permanent T-fragments for this wave: [kstep][plane]
    short8 Tfr[4][2];
    #pragma unroll
    for (int ks = 0; ks < 4; ++ks)
        #pragma unroll
        for (int pl = 0; pl < 2; ++pl)
            Tfr[ks][pl] = *(const short8*)(Tf + (((size_t)(wv * 4 + ks) * 2 + pl) << 9) + lane * 8);

    if (tid < 64) bias_s[tid] = (tid < OUT_DIM) ? bias[tid] : 0.f;

    f32x16 acc;
    #pragma unroll
    for (int i = 0; i < 16; ++i) acc[i] = 0.f;

    const int fcol = tid & 31, rblk = tid >> 5;   // staging map
    const int kst = rblk >> 1, lh = rblk & 1;     // hBf target
    const int nchunk = dpad >> 5;
    const int mtw = wv >> 1, ntw = wv & 1;        // ph4/epilogue tile

#define LOADCH(cn)                                                             \
    do {                                                                       \
        const int gf_ = (cn) * 32 + fcol;                                      \
        const bool fromx_ = ((cn) * 32 < IN_DIM);                              \
        _Pragma("unroll")                                                      \
        for (int p = 0; p < 8; ++p) {                                          \
            int r_ = rblk * 8 + p;                                             \
            float v_ = 0.f;                                                    \
            if (r_ < NODES && gf_ < d)                                         \
                v_ = fromx_ ? x[(size_t)(g * NODES + r_) * IN_DIM + gf_]       \
                            : X248[(size_t)(g * NODES + r_) * ACOLS + (gf_ - IN_DIM)]; \
            vh[p] = v_;                                                        \
        }                                                                      \
        const short8* wsrc_ = (const short8*)(WTf + (size_t)(cn) * 12288);     \
        _Pragma("unroll")                                                      \
        for (int i = 0; i < 6; ++i) breg[i] = wsrc_[i * 256 + tid];            \
    } while (0)

    float  vh[8];
    short8 breg[6];
    LOADCH(0);   // prologue

    for (int ch = 0; ch < nchunk; ++ch) {
        // ---- ph1: write staged data from registers
        {
            short8 hi8, lo8;
            #pragma unroll
            for (int p = 0; p < 8; ++p) {
                unsigned short h_, l_;
                tsplit(vh[p], h_, l_);
                hi8[p] = (short)h_; lo8[p] = (short)l_;
                hr[(rblk * 8 + p) * FSTR + fcol] = vh[p];
            }
            const int dlane = lh * 32 + fcol;
            *(short8*)&hBf[((kst * 2 + 0) << 9) + dlane * 8] = hi8;
            *(short8*)&hBf[((kst * 2 + 1) << 9) + dlane * 8] = lo8;
            #pragma unroll
            for (int i = 0; i < 6; ++i) ((short8*)Bs)[i * 256 + tid] = breg[i];
        }
        __syncthreads();   // A
        // ---- ph3: P = T@h (waves 0,1 -> T1 tiles; 2,3 -> T2 tiles)
        {
            f32x16 pacc;
            #pragma unroll
            for (int i = 0; i < 16; ++i) pacc[i] = 0.f;
            #pragma unroll
            for (int ks = 0; ks < 4; ++ks) {
                short8 bhi = *(const short8*)&hBf[((ks * 2 + 0) << 9) + lane * 8];
                short8 blo = *(const short8*)&hBf[((ks * 2 + 1) << 9) + lane * 8];
                pacc = __builtin_amdgcn_mfma_f32_32x32x16_bf16(Tfr[ks][0], bhi, pacc, 0, 0, 0);
                pacc = __builtin_amdgcn_mfma_f32_32x32x16_bf16(Tfr[ks][0], blo, pacc, 0, 0, 0);
                pacc = __builtin_amdgcn_mfma_f32_32x32x16_bf16(Tfr[ks][1], bhi, pacc, 0, 0, 0);
            }
            float* dst = (wv < 2) ? t1r : t2r;
            const int mbase = (wv & 1) * 32 + 4 * (lane >> 5);
            const int ccol  = lane & 31;
            #pragma unroll
            for (int reg = 0; reg < 16; ++reg) {
                int rr = mbase + (reg & 3) + 8 * (reg >> 2);
                dst[rr * FSTR + ccol] = pacc[reg];
            }
        }
        __syncthreads();   // B
        // ---- ph4: issue next-chunk loads (drain at barrier C), then MFMA
        {
            if (ch + 1 < nchunk) LOADCH(ch + 1);
            #pragma unroll
            for (int seg = 0; seg < 3; ++seg) {
                const float* src = (seg == 0) ? hr : (seg == 1) ? t1r : t2r;
                #pragma unroll
                for (int ks = 0; ks < 2; ++ks) {
                    const int kf = ks * 16 + (lane >> 5) * 8;
                    const float* ap = &src[(mtw * 32 + (lane & 31)) * FSTR + kf];
                    f32x4 u0 = *(const f32x4*)ap;
                    f32x4 u1 = *(const f32x4*)(ap + 4);
                    short8 ahi, alo;
                    #pragma unroll
                    for (int j = 0; j < 4; ++j) {
                        unsigned short h_, l_;
                        tsplit(u0[j], h_, l_); ahi[j] = (short)h_; alo[j] = (short)l_;
                        tsplit(u1[j], h_, l_); ahi[4 + j] = (short)h_; alo[4 + j] = (short)l_;
                    }
                    const unsigned short* bp =
                        Bs + ((((seg * 2 + ks) * 2 + 0) * 2 + ntw) << 9) + lane * 8;
                    short8 bhi = *(const short8*)bp;
                    short8 blo = *(const short8*)(bp + 1024);   // +1 plane = +2 frags
                    acc = __builtin_amdgcn_mfma_f32_32x32x16_bf16(ahi, bhi, acc, 0, 0, 0);
                    acc = __builtin_amdgcn_mfma_f32_32x32x16_bf16(ahi, blo, acc, 0, 0, 0);
                    acc = __builtin_amdgcn_mfma_f32_32x32x16_bf16(alo, bhi, acc, 0, 0, 0);
                }
            }
        }
        __syncthreads();   // C (protects hr/hBf/Bs/t1r/t2r overwrite)
    }
#undef LOADCH
    // epilogue: relu(acc + bias) -> X248[:, (d-128) .. (d-128)+62)
    {
        const int c = ntw * 32 + (lane & 31);
        if (c < OUT_DIM) {
            const int mbase = mtw * 32 + 4 * (lane >> 5);
            #pragma unroll
            for (int reg = 0; reg < 16; ++reg) {
                int m = mbase + (reg & 3) + 8 * (reg >> 2);
                if (m < NODES) {
                    float v = fmaxf(acc[reg] + bias_s[c], 0.f);
                    X248[(size_t)(g * NODES + m) * ACOLS + (d - IN_DIM) + c] = v;
                }
            }
        }
    }
}

// ---------------------------------------------------------------------------
// Head GEMM1, bf16 MFMA, 64x128 tile, split-K=8, SOFTWARE-PIPELINED:
// prologue load; per chunk: stage-from-regs -> barrier -> issue ch+1 loads
// -> 8 MFMA -> barrier. Loads drain one barrier later with MFMA in between.
// ---------------------------------------------------------------------------
#define SPLIT1 8
__global__ __launch_bounds__(256) void gemm_head1_mfma(
    const float* __restrict__ F32, const unsigned short* __restrict__ WT1,
    float* __restrict__ H1)
{
    __shared__ __align__(16) unsigned short A16[64 * BSTR];
    __shared__ __align__(16) unsigned short B16[128 * BSTR];
    const int tid  = threadIdx.x;
    const int lane = tid & 63;
    const int wv   = tid >> 6;
    const int bm = blockIdx.x, bnb = blockIdx.y, s = blockIdx.z;
    const int c0 = (481 * s) / SPLIT1, c1 = (481 * (s + 1)) / SPLIT1;
    const int mr = tid >> 2, kg = (tid & 3) * 8;      // A stage map
    const int mrB = tid >> 1, kgB = (tid & 1) * 16;   // B stage map

    f32x4 acc[8];
    #pragma unroll
    for (int i = 0; i < 8; ++i) acc[i] = (f32x4){0.f, 0.f, 0.f, 0.f};

    float4 u0, u1;
    short8 bv0, bv1;
#define LOAD1(cn)                                                              \
    do {                                                                       \
        const int k_ = (cn) * 32 + kg;                                         \
        u0 = (float4){0.f, 0.f, 0.f, 0.f};                                     \
        u1 = (float4){0.f, 0.f, 0.f, 0.f};                                     \
        bv0 = (short8){0, 0, 0, 0, 0, 0, 0, 0};                                \
        bv1 = (short8){0, 0, 0, 0, 0, 0, 0, 0};                                \
        if (k_ + 8 <= FEAT) {                                                  \
            const float4* p_ = (const float4*)&F32[(size_t)(bm * 64 + mr) * FEAT + k_]; \
            u0 = p_[0]; u1 = p_[1];                                            \
        }                                                                      \
        const int kB_ = (cn) * 32 + kgB;                                       \
        if (kB_ + 8 <= FEAT)                                                   \
            bv0 = *(const short8*)&WT1[(size_t)(bnb * 128 + mrB) * FEAT + kB_]; \
        if (kB_ + 16 <= FEAT)                                                  \
            bv1 = *(const short8*)&WT1[(size_t)(bnb * 128 + mrB) * FEAT + kB_ + 8]; \
    } while (0)

    LOAD1(c0);   // prologue
    for (int ch = c0; ch < c1; ++ch) {
        {
            short8 av;
            av[0] = (short)f2bf(u0.x); av[1] = (short)f2bf(u0.y);
            av[2] = (short)f2bf(u0.z); av[3] = (short)f2bf(u0.w);
            av[4] = (short)f2bf(u1.x); av[5] = (short)f2bf(u1.y);
            av[6] = (short)f2bf(u1.z); av[7] = (short)f2bf(u1.w);
            *(short8*)&A16[mr * BSTR + kg] = av;
            *(short8*)&B16[mrB * BSTR + kgB] = bv0;
            *(short8*)&B16[mrB * BSTR + kgB + 8] = bv1;
        }
        __syncthreads();
        if (ch + 1 < c1) LOAD1(ch + 1);
        short8 af = *(short8*)&A16[(wv * 16 + (lane & 15)) * BSTR + (lane >> 4) * 8];
        #pragma unroll
        for (int nt = 0; nt < 8; ++nt) {
            short8 bf = *(short8*)&B16[(nt * 16 + (lane & 15)) * BSTR + (lane >> 4) * 8];
            acc[nt] = __builtin_amdgcn_mfma_f32_16x16x32_bf16(af, bf, acc[nt], 0, 0, 0);
        }
        __syncthreads();
    }
#undef LOAD1
    const int m0 = bm * 64 + wv * 16 + (lane >> 4) * 4;
    #pragma unroll
    for (int nt = 0; nt < 8; ++nt) {
        int c = bnb * 128 + nt * 16 + (lane & 15);
        #pragma unroll
        for (int rg = 0; rg < 4; ++rg)
            atomicAdd(&H1[(size_t)(m0 + rg) * LIN1 + c], acc[nt][rg]);
    }
}

// ---------------------------------------------------------------------------
// GEMM2 fp32 (split-K=4): H2 += H1[2048,512] @ Wh2.
// ---------------------------------------------------------------------------
#define ACC16(av, bv) do {                              \
    acc[0][0] = fmaf((av).x, (bv).x, acc[0][0]);        \
    acc[0][1] = fmaf((av).x, (bv).y, acc[0][1]);        \
    acc[0][2] = fmaf((av).x, (bv).z, acc[0][2]);        \
    acc[0][3] = fmaf((av).x, (bv).w, acc[0][3]);        \
    acc[1][0] = fmaf((av).y, (bv).x, acc[1][0]);        \
    acc[1][1] = fmaf((av).y, (bv).y, acc[1][1]);        \
    acc[1][2] = fmaf((av).y, (bv).z, acc[1][2]);        \
    acc[1][3] = fmaf((av).y, (bv).w, acc[1][3]);        \
    acc[2][0] = fmaf((av).z, (bv).x, acc[2][0]);        \
    acc[2][1] = fmaf((av).z, (bv).y, acc[2][1]);        \
    acc[2][2] = fmaf((av).z, (bv).z, acc[2][2]);        \
    acc[2][3] = fmaf((av).z, (bv).w, acc[2][3]);        \
    acc[3][0] = fmaf((av).w, (bv).x, acc[3][0]);        \
    acc[3][1] = fmaf((av).w, (bv).y, acc[3][1]);        \
    acc[3][2] = fmaf((av).w, (bv).z, acc[3][2]);        \
    acc[3][3] = fmaf((av).w, (bv).w, acc[3][3]);        \
} while (0)

#define SPLIT2 4
__global__ __launch_bounds__(256) void gemm2_kernel(
    const float* __restrict__ A, const float* __restrict__ B,
    float* __restrict__ C)
{
    __shared__ __align__(16) float As[16 * 72];
    __shared__ __align__(16) float Bs[16 * 64];
    const int bm = blockIdx.x, bnb = blockIdx.y, s = blockIdx.z;
    const int tid = threadIdx.x;
    const int ty4 = (tid >> 4) * 4;
    const int tx4 = (tid & 15) * 4;
    const int kbeg = s * (LIN1 / SPLIT2);
    const int kend = kbeg + LIN1 / SPLIT2;
    float acc[4][4] = {};
    for (int k0 = kbeg; k0 < kend; k0 += 16) {
        for (int i = tid; i < 1024; i += 256) {
            int m = i >> 4, kt = i & 15;
            As[kt * 72 + m] = A[(size_t)(bm * 64 + m) * LIN1 + k0 + kt];
        }
        for (int i = tid; i < 1024; i += 256) {
            int kt = i >> 6, c = i & 63;
            Bs[kt * 64 + c] = B[(size_t)(k0 + kt) * LIN2 + bnb * 64 + c];
        }
        __syncthreads();
        #pragma unroll
        for (int kt = 0; kt < 16; ++kt) {
            const float4 av = *(const float4*)&As[kt * 72 + ty4];
            const float4 bv = *(const float4*)&Bs[kt * 64 + tx4];
            ACC16(av, bv);
        }
        __syncthreads();
    }
    const int b = bm * 64 + ty4, c = bnb * 64 + tx4;
    #pragma unroll
    for (int i = 0; i < 4; ++i)
        #pragma unroll
        for (int j = 0; j < 4; ++j)
            atomicAdd(&C[(size_t)(b + i) * LIN2 + c + j], acc[i][j]);
}

// ---------------------------------------------------------------------------
// BatchNorm (training stats, biased var) + ReLU, in place.
// ---------------------------------------------------------------------------
__global__ __launch_bounds__(256) void bn_relu_kernel(
    float* __restrict__ H, int C,
    const float* __restrict__ gamma, const float* __restrict__ beta)
{
    const int c  = blockIdx.x * 16 + (threadIdx.x & 15);
    const int rt = threadIdx.x >> 4;
    const int ct = threadIdx.x & 15;
    float s = 0.f, s2 = 0.f;
    for (int r = rt; r < BATCH; r += 16) {
        float v = H[(size_t)r * C + c];
        s += v; s2 += v * v;
    }
    __shared__ float Ss[16][16], S2s[16][16], sc_s[16], sh_s[16];
    Ss[rt][ct] = s; S2s[rt][ct] = s2;
    __syncthreads();
    if (rt == 0) {
        float ts = 0.f, ts2 = 0.f;
        #pragma unroll
        for (int i = 0; i < 16; ++i) { ts += Ss[i][ct]; ts2 += S2s[i][ct]; }
        float m   = ts * (1.f / BATCH);
        float var = ts2 * (1.f / BATCH) - m * m;
        float sc  = gamma[c] * rsqrtf(var + BN_EPS);
        sc_s[ct] = sc;
        sh_s[ct] = beta[c] - m * sc;
    }
    __syncthreads();
    const float sc = sc_s[ct], sh = sh_s[ct];
    for (int r = rt; r < BATCH; r += 16) {
        float v = H[(size_t)r * C + c];
        H[(size_t)r * C + c] = fmaxf(fmaf(v, sc, sh), 0.f);
    }
}

// ---------------------------------------------------------------------------
// Final: logits = H2 @ Wh3 + bh3, softmax over 3 classes.
// ---------------------------------------------------------------------------
__global__ __launch_bounds__(256) void final_kernel(
    const float* __restrict__ H2, const float* __restrict__ Wh3,
    const float* __restrict__ bh3, float* __restrict__ out)
{
    __shared__ float Ws[LIN2 * NCLS];
    __shared__ float bs[NCLS];
    const int tid = threadIdx.x;
    for (int i = tid; i < LIN2 * NCLS; i += 256) Ws[i] = Wh3[i];
    if (tid < NCLS) bs[tid] = bh3[tid];
    __syncthreads();
    const int r = blockIdx.x * 256 + tid;
    float a0 = bs[0], a1 = bs[1], a2 = bs[2];
    const float4* row = (const float4*)&H2[(size_t)r * LIN2];
    for (int k4 = 0; k4 < LIN2 / 4; ++k4) {
        float4 h = row[k4];
        int k = k4 * 4;
        a0 = fmaf(h.x, Ws[(k + 0) * 3 + 0], a0);
        a1 = fmaf(h.x, Ws[(k + 0) * 3 + 1], a1);
        a2 = fmaf(h.x, Ws[(k + 0) * 3 + 2], a2);
        a0 = fmaf(h.y, Ws[(k + 1) * 3 + 0], a0);
        a1 = fmaf(h.y, Ws[(k + 1) * 3 + 1], a1);
        a2 = fmaf(h.y, Ws[(k + 1) * 3 + 2], a2);
        a0 = fmaf(h.z, Ws[(k + 2) * 3 + 0], a0);
        a1 = fmaf(h.z, Ws[(k + 2) * 3 + 1], a1);
        a2 = fmaf(h.z, Ws[(k + 2) * 3 + 2], a2);
        a0 = fmaf(h.w, Ws[(k + 3) * 3 + 0], a0);
        a1 = fmaf(h.w, Ws[(k + 3) * 3 + 1], a1);
        a2 = fmaf(h.w, Ws[(k + 3) * 3 + 2], a2);
    }
    float mx = fmaxf(a0, fmaxf(a1, a2));
    float e0 = expf(a0 - mx), e1 = expf(a1 - mx), e2 = expf(a2 - mx);
    float inv = 1.f / (e0 + e1 + e2);
    out[r * 3 + 0] = e0 * inv;
    out[r * 3 + 1] = e1 * inv;
    out[r * 3 + 2] = e2 * inv;
}

// ---------------------------------------------------------------------------
extern "C" void kernel_launch(void* const* d_in, const int* in_sizes, int n_in,
                              void* d_out, int out_size, void* d_ws, size_t ws_size,
                              hipStream_t stream)
{
    const float* x   = (const float*)d_in[0];
    const int*   ei  = (const int*)  d_in[1];
    const float* W1  = (const float*)d_in[2];
    const float* b1  = (const float*)d_in[3];
    const float* W2  = (const float*)d_in[4];
    const float* b2  = (const float*)d_in[5];
    const float* W3  = (const float*)d_in[6];
    const float* b3  = (const float*)d_in[7];
    const float* W4  = (const float*)d_in[8];
    const float* b4  = (const float*)d_in[9];
    const float* Wh1 = (const float*)d_in[10];
    const float* bh1 = (const float*)d_in[11];
    const float* g1  = (const float*)d_in[12];
    const float* be1 = (const float*)d_in[13];
    const float* Wh2 = (const float*)d_in[14];
    const float* bh2 = (const float*)d_in[15];
    const float* g2  = (const float*)d_in[16];
    const float* be2 = (const float*)d_in[17];
    const float* Wh3 = (const float*)d_in[18];
    const float* bh3 = (const float*)d_in[19];
    float* out = (float*)d_out;

    // workspace layout -- TOTAL ~142 MB (R8-proven)
    char* ws = (char*)d_ws;
    unsigned short* Tf   = (unsigned short*)(ws + 32768);            // 32768
    unsigned short* WT1c = (unsigned short*)(ws + 65536);            // 98304   (4 ch)
    unsigned short* WT2c = (unsigned short*)(ws + 163840);           // 147456  (6 ch)
    unsigned short* WT3c = (unsigned short*)(ws + 311296);           // 196608  (8 ch)
    unsigned short* WT4c = (unsigned short*)(ws + 507904);           // 245760  (10 ch)
    unsigned short* Wh1T = (unsigned short*)(ws + 753664);           // 15,745,024
    float* X248 = (float*)(ws + 16498688);                           // 125,960,192
    float* H1   = (float*)(ws + 142458880);                          // 4,194,304
    float* H2   = (float*)(ws + 146653184);                          // 2,097,152

    const int E   = in_sizes[1] / 2;   // 1,015,808
    const int epg = E / BATCH;         // 496 edges of graph 0

    build_LT_convT<<<1, 256, 0, stream>>>(ei, E, epg, Tf);
    conv_wcheb_all<<<dim3(480, 4), 256, 0, stream>>>(W1, W2, W3, W4,
                                                     WT1c, WT2c, WT3c, WT4c);
    transpose_wh1<<<dim3(481, 16), 256, 0, stream>>>(Wh1, Wh1T);

    cheb_mfma<<<BATCH, 256, 0, stream>>>(x, X248, WT1c, Tf, b1, 128, 128);
    cheb_mfma<<<BATCH, 256, 0, stream>>>(x, X248, WT2c, Tf, b2, 190, 192);
    cheb_mfma<<<BATCH, 256, 0, stream>>>(x, X248, WT3c, Tf, b3, 252, 256);
    cheb_mfma<<<BATCH, 256, 0, stream>>>(x, X248, WT4c, Tf, b4, 314, 320);

    init_bias<<<(BATCH * LIN1 / 4 + 255) / 256, 256, 0, stream>>>(H1, bh1, LIN1 / 4 - 1, BATCH * LIN1 / 4);
    gemm_head1_mfma<<<dim3(32, 4, SPLIT1), 256, 0, stream>>>(X248, Wh1T, H1);
    bn_relu_kernel<<<LIN1 / 16, 256, 0, stream>>>(H1, LIN1, g1, be1);

    init_bias<<<(BATCH * LIN2 / 4 + 255) / 256, 256, 0, stream>>>(H2, bh2, LIN2 / 4 - 1, BATCH * LIN2 / 4);
    gemm2_kernel<<<dim3(32, 4, SPLIT2), 256, 0, stream>>>(H1, Wh2, H2);
    bn_relu_kernel<<<LIN2 / 16, 256, 0, stream>>>(H2, LIN2, g2, be2);

    final_kernel<<<BATCH / 256, 256, 0, stream>>>(H2, Wh3, bh3, out);
}